// Round 1
// baseline (1273.203 us; speedup 1.0000x reference)
//
#include <hip/hip_runtime.h>
#include <math.h>

#define NSP 4096      // h*w*z = 16^3
#define CD 128        // channels
#define NBATCH 2
#define NHEADS 4
#define DH 32         // head dim
#define JS 4          // j-splits for attention parallelism
#define ATT_BLK 256
#define QPT 2         // queries per thread
#define IT (ATT_BLK*QPT)   // 512 queries per block

static constexpr float LOG2E_F = 1.4426950408889634f;
static constexpr float QSCALE = 10.0f * LOG2E_F;   // fold attn scale + log2(e) into q

// ---------------- projection: O[b][o][n] = sum_c W[o][c] * X[b][c][n] + B[o] ----------------
// grid: (NSP/256, CD/4, NBATCH), block 256. Each thread: 4 output rows for one n.
template <bool DUAL>
__global__ __launch_bounds__(256) void proj_kernel(
    const float* __restrict__ X,
    const float* __restrict__ W1, const float* __restrict__ B1, float* __restrict__ O1,
    const float* __restrict__ W2, const float* __restrict__ B2, float* __restrict__ O2)
{
    const int n  = blockIdx.x * 256 + threadIdx.x;
    const int o0 = blockIdx.y * 4;
    const int b  = blockIdx.z;
    const float* Xb = X + ((size_t)b * CD) * NSP + n;

    float a1[4], a2[4];
    #pragma unroll
    for (int r = 0; r < 4; ++r) a1[r] = B1[o0 + r];
    if (DUAL) {
        #pragma unroll
        for (int r = 0; r < 4; ++r) a2[r] = B2[o0 + r];
    }
    for (int c = 0; c < CD; ++c) {
        const float xv = Xb[(size_t)c * NSP];
        #pragma unroll
        for (int r = 0; r < 4; ++r) a1[r] = fmaf(W1[(o0 + r) * CD + c], xv, a1[r]);
        if (DUAL) {
            #pragma unroll
            for (int r = 0; r < 4; ++r) a2[r] = fmaf(W2[(o0 + r) * CD + c], xv, a2[r]);
        }
    }
    #pragma unroll
    for (int r = 0; r < 4; ++r)
        O1[((size_t)b * CD + o0 + r) * NSP + n] = a1[r];
    if (DUAL) {
        #pragma unroll
        for (int r = 0; r < 4; ++r)
            O2[((size_t)b * CD + o0 + r) * NSP + n] = a2[r];
    }
}

// ---------------- per-(b,c)-row L2 normalize over N, with scale fold ----------------
// grid: (CD, NBATCH, 2) -> z=0: q row scaled by QSCALE/||row||; z=1: k row scaled by 1/||row||
__global__ __launch_bounds__(256) void normscale_kernel(float* __restrict__ Q, float* __restrict__ K)
{
    float* T = (blockIdx.z == 0) ? Q : K;
    const float mult = (blockIdx.z == 0) ? QSCALE : 1.0f;
    float* row = T + ((size_t)blockIdx.y * CD + blockIdx.x) * NSP;
    const int t = threadIdx.x;

    float ss = 0.f;
    for (int i = t * 4; i < NSP; i += 256 * 4) {
        float4 v = *(const float4*)&row[i];
        ss = fmaf(v.x, v.x, fmaf(v.y, v.y, fmaf(v.z, v.z, fmaf(v.w, v.w, ss))));
    }
    #pragma unroll
    for (int off = 32; off > 0; off >>= 1) ss += __shfl_down(ss, off, 64);
    __shared__ float red[4];
    if ((t & 63) == 0) red[t >> 6] = ss;
    __syncthreads();
    const float total = red[0] + red[1] + red[2] + red[3];
    const float sc = mult / fmaxf(sqrtf(total), 1e-12f);
    for (int i = t * 4; i < NSP; i += 256 * 4) {
        float4 v = *(const float4*)&row[i];
        v.x *= sc; v.y *= sc; v.z *= sc; v.w *= sc;
        *(float4*)&row[i] = v;
    }
}

// ---------------- flash attention partials (fp32 vector) ----------------
// grid: (NSP/IT, NBATCH*NHEADS, JS), block 256. Each thread owns 2 queries.
// q already holds 10*log2e * q_normalized; k holds k_normalized -> s' = log2e * sim.
__global__ __launch_bounds__(256) void attn_kernel(
    const float* __restrict__ q, const float* __restrict__ k, const float* __restrict__ v,
    float* __restrict__ pacc, float* __restrict__ pm, float* __restrict__ pl)
{
    const int itile = blockIdx.x;
    const int bh    = blockIdx.y;         // b*4 + h
    const int js    = blockIdx.z;
    const int t     = threadIdx.x;
    const int b = bh >> 2, h = bh & 3;
    const size_t chan0 = ((size_t)b * CD + h * DH) * NSP;
    const float* Qb = q + chan0;
    const float* Kb = k + chan0;
    const float* Vb = v + chan0;

    const int ia = itile * IT + t;
    const int ib = ia + 256;

    float q0[DH], q1[DH], a0[DH], a1[DH];
    #pragma unroll
    for (int d = 0; d < DH; ++d) {
        q0[d] = Qb[(size_t)d * NSP + ia];
        q1[d] = Qb[(size_t)d * NSP + ib];
        a0[d] = 0.f; a1[d] = 0.f;
    }
    float m0 = -1e30f, m1 = -1e30f, l0 = 0.f, l1 = 0.f;

    const int j_begin = js * (NSP / JS);
    const int j_end   = j_begin + (NSP / JS);
    for (int j0 = j_begin; j0 < j_end; j0 += 8) {
        float s0[8] = {0,0,0,0,0,0,0,0};
        float s1[8] = {0,0,0,0,0,0,0,0};
        #pragma unroll
        for (int d = 0; d < DH; ++d) {
            const float4 ka = *(const float4*)(Kb + (size_t)d * NSP + j0);
            const float4 kb = *(const float4*)(Kb + (size_t)d * NSP + j0 + 4);
            const float qa = q0[d], qb = q1[d];
            s0[0] = fmaf(qa, ka.x, s0[0]); s0[1] = fmaf(qa, ka.y, s0[1]);
            s0[2] = fmaf(qa, ka.z, s0[2]); s0[3] = fmaf(qa, ka.w, s0[3]);
            s0[4] = fmaf(qa, kb.x, s0[4]); s0[5] = fmaf(qa, kb.y, s0[5]);
            s0[6] = fmaf(qa, kb.z, s0[6]); s0[7] = fmaf(qa, kb.w, s0[7]);
            s1[0] = fmaf(qb, ka.x, s1[0]); s1[1] = fmaf(qb, ka.y, s1[1]);
            s1[2] = fmaf(qb, ka.z, s1[2]); s1[3] = fmaf(qb, ka.w, s1[3]);
            s1[4] = fmaf(qb, kb.x, s1[4]); s1[5] = fmaf(qb, kb.y, s1[5]);
            s1[6] = fmaf(qb, kb.z, s1[6]); s1[7] = fmaf(qb, kb.w, s1[7]);
        }
        const float cm0 = fmaxf(fmaxf(fmaxf(s0[0],s0[1]), fmaxf(s0[2],s0[3])),
                                fmaxf(fmaxf(s0[4],s0[5]), fmaxf(s0[6],s0[7])));
        const float cm1 = fmaxf(fmaxf(fmaxf(s1[0],s1[1]), fmaxf(s1[2],s1[3])),
                                fmaxf(fmaxf(s1[4],s1[5]), fmaxf(s1[6],s1[7])));
        if (cm0 > m0) {
            const float r = exp2f(m0 - cm0); m0 = cm0; l0 *= r;
            #pragma unroll
            for (int d = 0; d < DH; ++d) a0[d] *= r;
        }
        if (cm1 > m1) {
            const float r = exp2f(m1 - cm1); m1 = cm1; l1 *= r;
            #pragma unroll
            for (int d = 0; d < DH; ++d) a1[d] *= r;
        }
        float p0[8], p1[8];
        #pragma unroll
        for (int jj = 0; jj < 8; ++jj) { p0[jj] = exp2f(s0[jj] - m0); l0 += p0[jj]; }
        #pragma unroll
        for (int jj = 0; jj < 8; ++jj) { p1[jj] = exp2f(s1[jj] - m1); l1 += p1[jj]; }
        #pragma unroll
        for (int d = 0; d < DH; ++d) {
            const float4 va = *(const float4*)(Vb + (size_t)d * NSP + j0);
            const float4 vb = *(const float4*)(Vb + (size_t)d * NSP + j0 + 4);
            a0[d] = fmaf(p0[0], va.x, a0[d]); a0[d] = fmaf(p0[1], va.y, a0[d]);
            a0[d] = fmaf(p0[2], va.z, a0[d]); a0[d] = fmaf(p0[3], va.w, a0[d]);
            a0[d] = fmaf(p0[4], vb.x, a0[d]); a0[d] = fmaf(p0[5], vb.y, a0[d]);
            a0[d] = fmaf(p0[6], vb.z, a0[d]); a0[d] = fmaf(p0[7], vb.w, a0[d]);
            a1[d] = fmaf(p1[0], va.x, a1[d]); a1[d] = fmaf(p1[1], va.y, a1[d]);
            a1[d] = fmaf(p1[2], va.z, a1[d]); a1[d] = fmaf(p1[3], va.w, a1[d]);
            a1[d] = fmaf(p1[4], vb.x, a1[d]); a1[d] = fmaf(p1[5], vb.y, a1[d]);
            a1[d] = fmaf(p1[6], vb.z, a1[d]); a1[d] = fmaf(p1[7], vb.w, a1[d]);
        }
    }
    const size_t base = (size_t)(js * 8 + bh);
    pm[base * NSP + ia] = m0; pm[base * NSP + ib] = m1;
    pl[base * NSP + ia] = l0; pl[base * NSP + ib] = l1;
    #pragma unroll
    for (int d = 0; d < DH; ++d) {
        pacc[(base * DH + d) * NSP + ia] = a0[d];
        pacc[(base * DH + d) * NSP + ib] = a1[d];
    }
}

// ---------------- combine j-split partials -> attnout[b][h*32+d][n] ----------------
// grid: (NSP/256, NBATCH*NHEADS), block 256
__global__ __launch_bounds__(256) void combine_kernel(
    const float* __restrict__ pacc, const float* __restrict__ pm, const float* __restrict__ pl,
    float* __restrict__ attnout)
{
    const int i  = blockIdx.x * 256 + threadIdx.x;
    const int bh = blockIdx.y;
    const int b = bh >> 2, h = bh & 3;

    float mv[JS], f[JS];
    float M = -1e30f;
    #pragma unroll
    for (int s = 0; s < JS; ++s) {
        mv[s] = pm[((size_t)(s * 8 + bh)) * NSP + i];
        M = fmaxf(M, mv[s]);
    }
    float L = 0.f;
    #pragma unroll
    for (int s = 0; s < JS; ++s) {
        f[s] = exp2f(mv[s] - M);
        L += pl[((size_t)(s * 8 + bh)) * NSP + i] * f[s];
    }
    const float invL = 1.0f / L;
    #pragma unroll
    for (int d = 0; d < DH; ++d) {
        float acc = 0.f;
        #pragma unroll
        for (int s = 0; s < JS; ++s)
            acc += pacc[(((size_t)(s * 8 + bh)) * DH + d) * NSP + i] * f[s];
        attnout[((size_t)b * CD + h * DH + d) * NSP + i] = acc * invL;
    }
}

extern "C" void kernel_launch(void* const* d_in, const int* in_sizes, int n_in,
                              void* d_out, int out_size, void* d_ws, size_t ws_size,
                              hipStream_t stream)
{
    const float* x  = (const float*)d_in[0];
    const float* cx = (const float*)d_in[1];
    const float* Wq = (const float*)d_in[2];
    const float* bq = (const float*)d_in[3];
    const float* Wk = (const float*)d_in[4];
    const float* bk = (const float*)d_in[5];
    const float* Wv = (const float*)d_in[6];
    const float* bv = (const float*)d_in[7];
    const float* Wo = (const float*)d_in[8];
    const float* bo = (const float*)d_in[9];
    float* out = (float*)d_out;

    float* ws = (float*)d_ws;
    const size_t PLANE = (size_t)NBATCH * CD * NSP;   // 1,048,576 floats
    float* qb   = ws;
    float* kb   = qb + PLANE;
    float* vb   = kb + PLANE;
    float* pacc = vb + PLANE;                          // JS*8*DH*NSP = 4,194,304
    float* pm   = pacc + (size_t)JS * 8 * DH * NSP;    // 131,072
    float* pl   = pm + (size_t)JS * 8 * NSP;           // 131,072
    float* attnout = pl + (size_t)JS * 8 * NSP;        // 1,048,576

    dim3 pgrid(NSP / 256, CD / 4, NBATCH);
    // q = Wq x + bq ; k,v = Wk/Wv cond + b
    proj_kernel<false><<<pgrid, 256, 0, stream>>>(x,  Wq, bq, qb, nullptr, nullptr, nullptr);
    proj_kernel<true ><<<pgrid, 256, 0, stream>>>(cx, Wk, bk, kb, Wv, bv, vb);
    // normalize q,k rows over spatial axis; fold 10*log2(e) into q
    normscale_kernel<<<dim3(CD, NBATCH, 2), 256, 0, stream>>>(qb, kb);
    // flash attention partials
    attn_kernel<<<dim3(NSP / IT, NBATCH * NHEADS, JS), ATT_BLK, 0, stream>>>(qb, kb, vb, pacc, pm, pl);
    // combine partials
    combine_kernel<<<dim3(NSP / 256, NBATCH * NHEADS), 256, 0, stream>>>(pacc, pm, pl, attnout);
    // output projection
    proj_kernel<false><<<pgrid, 256, 0, stream>>>(attnout, Wo, bo, out, nullptr, nullptr, nullptr);
}

// Round 2
// 112.343 us; speedup vs baseline: 11.3332x; 11.3332x over previous
//
#include <hip/hip_runtime.h>
#include <math.h>

#define NSP 4096      // h*w*z = 16^3
#define CD 128        // channels
#define NB 2          // batch
#define NH 4          // heads
#define JS 4          // j-splits in attention

typedef __attribute__((ext_vector_type(8))) short bf16x8;   // 8 bf16 (4 VGPRs)
typedef __attribute__((ext_vector_type(4))) float f32x4;

static constexpr float QSCALE = 10.0f * 1.4426950408889634f;  // scale * log2(e)

__device__ __forceinline__ ushort f2bf(float f) {
    union { float f; unsigned u; } v; v.f = f;
    unsigned r = v.u + 0x7fffu + ((v.u >> 16) & 1u);   // RNE, finite inputs only
    return (ushort)(r >> 16);
}

// ---------------- projection (fp32 out): O[b][o][n] = sum_c W[o][c] X[b][c][n] + B[o] ----
__global__ __launch_bounds__(256) void proj_one(
    const float* __restrict__ X, const float* __restrict__ W,
    const float* __restrict__ Bi, float* __restrict__ O)
{
    const int n  = blockIdx.x * 256 + threadIdx.x;
    const int o0 = blockIdx.y * 4;
    const int b  = blockIdx.z;
    const float* Xb = X + (size_t)b * CD * NSP + n;
    float a[4];
    #pragma unroll
    for (int r = 0; r < 4; ++r) a[r] = Bi[o0 + r];
    for (int c = 0; c < CD; ++c) {
        const float xv = Xb[(size_t)c * NSP];
        #pragma unroll
        for (int r = 0; r < 4; ++r) a[r] = fmaf(W[(o0 + r) * CD + c], xv, a[r]);
    }
    #pragma unroll
    for (int r = 0; r < 4; ++r) O[((size_t)b * CD + o0 + r) * NSP + n] = a[r];
}

// ---------------- k (fp32) + v (bf16, [b][c][n] layout) in one pass ----------------
__global__ __launch_bounds__(256) void proj_kv(
    const float* __restrict__ X,
    const float* __restrict__ Wk, const float* __restrict__ Bk, float* __restrict__ K,
    const float* __restrict__ Wv, const float* __restrict__ Bv, ushort* __restrict__ V16)
{
    const int n  = blockIdx.x * 256 + threadIdx.x;
    const int o0 = blockIdx.y * 4;
    const int b  = blockIdx.z;
    const float* Xb = X + (size_t)b * CD * NSP + n;
    float ak[4], av[4];
    #pragma unroll
    for (int r = 0; r < 4; ++r) { ak[r] = Bk[o0 + r]; av[r] = Bv[o0 + r]; }
    for (int c = 0; c < CD; ++c) {
        const float xv = Xb[(size_t)c * NSP];
        #pragma unroll
        for (int r = 0; r < 4; ++r) {
            ak[r] = fmaf(Wk[(o0 + r) * CD + c], xv, ak[r]);
            av[r] = fmaf(Wv[(o0 + r) * CD + c], xv, av[r]);
        }
    }
    #pragma unroll
    for (int r = 0; r < 4; ++r) {
        K[((size_t)b * CD + o0 + r) * NSP + n]   = ak[r];
        V16[((size_t)b * CD + o0 + r) * NSP + n] = f2bf(av[r]);
    }
}

// ---------------- per-(b,c)-row L2 norm scales over spatial N ----------------
__global__ __launch_bounds__(256) void rownorm(
    const float* __restrict__ qb, const float* __restrict__ kb,
    float* __restrict__ scq, float* __restrict__ sck)
{
    const int c = blockIdx.x, b = blockIdx.y, which = blockIdx.z;
    const float* row = (which ? kb : qb) + ((size_t)b * CD + c) * NSP;
    const int t = threadIdx.x;
    float ss = 0.f;
    for (int i = t * 4; i < NSP; i += 1024) {
        float4 v = *(const float4*)&row[i];
        ss = fmaf(v.x, v.x, fmaf(v.y, v.y, fmaf(v.z, v.z, fmaf(v.w, v.w, ss))));
    }
    #pragma unroll
    for (int off = 32; off > 0; off >>= 1) ss += __shfl_down(ss, off, 64);
    __shared__ float red[4];
    if ((t & 63) == 0) red[t >> 6] = ss;
    __syncthreads();
    if (t == 0) {
        const float total = red[0] + red[1] + red[2] + red[3];
        const float sc = (which ? 1.0f : QSCALE) / fmaxf(sqrtf(total), 1e-12f);
        (which ? sck : scq)[b * CD + c] = sc;
    }
}

// ---------------- pack q,k -> bf16 [bh][n][32] (n-major rows of head-dim) ----------------
__global__ __launch_bounds__(256) void pack_qk(
    const float* __restrict__ qb, const float* __restrict__ kb,
    const float* __restrict__ scq, const float* __restrict__ sck,
    ushort* __restrict__ Qt, ushort* __restrict__ Kt)
{
    const int n  = blockIdx.x * 256 + threadIdx.x;
    const int bh = blockIdx.y;
    const int b = bh >> 2, h = bh & 3;
    unsigned qw[16], kw[16];
    #pragma unroll
    for (int dp = 0; dp < 16; ++dp) {
        const int gr = b * CD + h * 32 + 2 * dp;
        const float fq0 = qb[(size_t)gr * NSP + n] * scq[gr];
        const float fq1 = qb[(size_t)(gr + 1) * NSP + n] * scq[gr + 1];
        const float fk0 = kb[(size_t)gr * NSP + n] * sck[gr];
        const float fk1 = kb[(size_t)(gr + 1) * NSP + n] * sck[gr + 1];
        qw[dp] = (unsigned)f2bf(fq0) | ((unsigned)f2bf(fq1) << 16);
        kw[dp] = (unsigned)f2bf(fk0) | ((unsigned)f2bf(fk1) << 16);
    }
    const size_t o = ((size_t)bh * NSP + n) * 32;
    #pragma unroll
    for (int j = 0; j < 4; ++j) {
        *(uint4*)(Qt + o + j * 8) = make_uint4(qw[4*j], qw[4*j+1], qw[4*j+2], qw[4*j+3]);
        *(uint4*)(Kt + o + j * 8) = make_uint4(kw[4*j], kw[4*j+1], kw[4*j+2], kw[4*j+3]);
    }
}

// ---------------- MFMA flash attention partials ----------------
// grid (NSP/128, NB*NH, JS), block 256 (4 waves). Each wave: 32 queries, j-range NSP/JS.
// Qt,Kt: [bh][n][32] bf16. V16: [b][c][n] bf16.
// Swapped QK^T: S^T-tile = mfma(Kfrag, Qfrag) -> lane holds query n16=lane&15, j = 4g+r.
// P via per-wave LDS round-trip -> B-frag of PV (O^T = V * P^T).
__global__ __launch_bounds__(256, 4) void attn_mfma(
    const ushort* __restrict__ Qt, const ushort* __restrict__ Kt,
    const ushort* __restrict__ V16,
    float* __restrict__ pacc, float* __restrict__ pm, float* __restrict__ pl)
{
    __shared__ __align__(16) ushort plds[4][16][40];   // per-wave P tile, pad 32->40
    const int t = threadIdx.x;
    const int wid = t >> 6, lane = t & 63;
    const int g = lane >> 4, n16 = lane & 15;
    const int bh = blockIdx.y, js = blockIdx.z;
    const int b = bh >> 2, h = bh & 3;
    const int i0 = (blockIdx.x * 4 + wid) * 32;

    const ushort* Qb = Qt + (size_t)bh * NSP * 32;
    const ushort* Kb = Kt + (size_t)bh * NSP * 32;
    const ushort* Vb = V16 + (size_t)(b * CD + h * 32) * NSP;

    const bf16x8 qf0 = *(const bf16x8*)(Qb + (size_t)(i0 + n16) * 32 + g * 8);
    const bf16x8 qf1 = *(const bf16x8*)(Qb + (size_t)(i0 + 16 + n16) * 32 + g * 8);

    f32x4 acc00 = {0,0,0,0}, acc01 = {0,0,0,0}, acc10 = {0,0,0,0}, acc11 = {0,0,0,0};
    float m0 = -1e30f, m1 = -1e30f, l0 = 0.f, l1 = 0.f;

    ushort* prow = &plds[wid][n16][0];
    const f32x4 zero = {0,0,0,0};

    const int jbeg = js * (NSP / JS), jend = jbeg + NSP / JS;
    for (int jt = jbeg; jt < jend; jt += 32) {
        const bf16x8 kf0 = *(const bf16x8*)(Kb + (size_t)(jt + n16) * 32 + g * 8);
        const bf16x8 kf1 = *(const bf16x8*)(Kb + (size_t)(jt + 16 + n16) * 32 + g * 8);
        const bf16x8 vf0 = *(const bf16x8*)(Vb + (size_t)n16 * NSP + jt + g * 8);
        const bf16x8 vf1 = *(const bf16x8*)(Vb + (size_t)(16 + n16) * NSP + jt + g * 8);

        // ---------- i-tile 0 ----------
        {
            f32x4 s0 = __builtin_amdgcn_mfma_f32_16x16x32_bf16(kf0, qf0, zero, 0, 0, 0);
            f32x4 s1 = __builtin_amdgcn_mfma_f32_16x16x32_bf16(kf1, qf0, zero, 0, 0, 0);
            float pmax = fmaxf(fmaxf(fmaxf(s0.x, s0.y), fmaxf(s0.z, s0.w)),
                               fmaxf(fmaxf(s1.x, s1.y), fmaxf(s1.z, s1.w)));
            pmax = fmaxf(pmax, __shfl_xor(pmax, 16));
            pmax = fmaxf(pmax, __shfl_xor(pmax, 32));
            const float mn = fmaxf(m0, pmax);
            const float rs = __builtin_amdgcn_exp2f(m0 - mn);
            m0 = mn;
            const float p0 = __builtin_amdgcn_exp2f(s0.x - mn);
            const float p1 = __builtin_amdgcn_exp2f(s0.y - mn);
            const float p2 = __builtin_amdgcn_exp2f(s0.z - mn);
            const float p3 = __builtin_amdgcn_exp2f(s0.w - mn);
            const float p4 = __builtin_amdgcn_exp2f(s1.x - mn);
            const float p5 = __builtin_amdgcn_exp2f(s1.y - mn);
            const float p6 = __builtin_amdgcn_exp2f(s1.z - mn);
            const float p7 = __builtin_amdgcn_exp2f(s1.w - mn);
            float ps = ((p0 + p1) + (p2 + p3)) + ((p4 + p5) + (p6 + p7));
            ps += __shfl_xor(ps, 16);
            ps += __shfl_xor(ps, 32);
            l0 = l0 * rs + ps;
            acc00 *= rs; acc01 *= rs;
            ushort4 w0; w0.x = f2bf(p0); w0.y = f2bf(p1); w0.z = f2bf(p2); w0.w = f2bf(p3);
            ushort4 w1; w1.x = f2bf(p4); w1.y = f2bf(p5); w1.z = f2bf(p6); w1.w = f2bf(p7);
            *(ushort4*)(prow + 4 * g)      = w0;   // cols 4g..4g+3   (j = jt+4g+r)
            *(ushort4*)(prow + 16 + 4 * g) = w1;   // cols 16+4g..    (j = jt+16+4g+r)
            const bf16x8 pf = *(const bf16x8*)(prow + 8 * g);   // cols 8g..8g+7
            acc00 = __builtin_amdgcn_mfma_f32_16x16x32_bf16(vf0, pf, acc00, 0, 0, 0);
            acc01 = __builtin_amdgcn_mfma_f32_16x16x32_bf16(vf1, pf, acc01, 0, 0, 0);
        }
        // ---------- i-tile 1 ----------
        {
            f32x4 s0 = __builtin_amdgcn_mfma_f32_16x16x32_bf16(kf0, qf1, zero, 0, 0, 0);
            f32x4 s1 = __builtin_amdgcn_mfma_f32_16x16x32_bf16(kf1, qf1, zero, 0, 0, 0);
            float pmax = fmaxf(fmaxf(fmaxf(s0.x, s0.y), fmaxf(s0.z, s0.w)),
                               fmaxf(fmaxf(s1.x, s1.y), fmaxf(s1.z, s1.w)));
            pmax = fmaxf(pmax, __shfl_xor(pmax, 16));
            pmax = fmaxf(pmax, __shfl_xor(pmax, 32));
            const float mn = fmaxf(m1, pmax);
            const float rs = __builtin_amdgcn_exp2f(m1 - mn);
            m1 = mn;
            const float p0 = __builtin_amdgcn_exp2f(s0.x - mn);
            const float p1 = __builtin_amdgcn_exp2f(s0.y - mn);
            const float p2 = __builtin_amdgcn_exp2f(s0.z - mn);
            const float p3 = __builtin_amdgcn_exp2f(s0.w - mn);
            const float p4 = __builtin_amdgcn_exp2f(s1.x - mn);
            const float p5 = __builtin_amdgcn_exp2f(s1.y - mn);
            const float p6 = __builtin_amdgcn_exp2f(s1.z - mn);
            const float p7 = __builtin_amdgcn_exp2f(s1.w - mn);
            float ps = ((p0 + p1) + (p2 + p3)) + ((p4 + p5) + (p6 + p7));
            ps += __shfl_xor(ps, 16);
            ps += __shfl_xor(ps, 32);
            l1 = l1 * rs + ps;
            acc10 *= rs; acc11 *= rs;
            ushort4 w0; w0.x = f2bf(p0); w0.y = f2bf(p1); w0.z = f2bf(p2); w0.w = f2bf(p3);
            ushort4 w1; w1.x = f2bf(p4); w1.y = f2bf(p5); w1.z = f2bf(p6); w1.w = f2bf(p7);
            *(ushort4*)(prow + 4 * g)      = w0;
            *(ushort4*)(prow + 16 + 4 * g) = w1;
            const bf16x8 pf = *(const bf16x8*)(prow + 8 * g);
            acc10 = __builtin_amdgcn_mfma_f32_16x16x32_bf16(vf0, pf, acc10, 0, 0, 0);
            acc11 = __builtin_amdgcn_mfma_f32_16x16x32_bf16(vf1, pf, acc11, 0, 0, 0);
        }
    }

    const size_t base = (size_t)js * 8 + bh;
    if (lane < 16) {
        pm[base * NSP + i0 + n16]      = m0;
        pm[base * NSP + i0 + 16 + n16] = m1;
        pl[base * NSP + i0 + n16]      = l0;
        pl[base * NSP + i0 + 16 + n16] = l1;
    }
    float* pb = pacc + base * 32 * NSP;
    #pragma unroll
    for (int r = 0; r < 4; ++r) {
        const int d0 = 4 * g + r, d1 = 16 + 4 * g + r;
        pb[(size_t)d0 * NSP + i0 + n16]      = acc00[r];
        pb[(size_t)d1 * NSP + i0 + n16]      = acc01[r];
        pb[(size_t)d0 * NSP + i0 + 16 + n16] = acc10[r];
        pb[(size_t)d1 * NSP + i0 + 16 + n16] = acc11[r];
    }
}

// ---------------- combine j-split partials -> attnout[b][h*32+d][n] fp32 ----------------
__global__ __launch_bounds__(256) void combine_kernel(
    const float* __restrict__ pacc, const float* __restrict__ pm, const float* __restrict__ pl,
    float* __restrict__ attnout)
{
    const int i  = blockIdx.x * 256 + threadIdx.x;
    const int bh = blockIdx.y;
    const int b = bh >> 2, h = bh & 3;
    float mv[JS], f[JS];
    float M = -1e30f;
    #pragma unroll
    for (int s = 0; s < JS; ++s) {
        mv[s] = pm[((size_t)(s * 8 + bh)) * NSP + i];
        M = fmaxf(M, mv[s]);
    }
    float L = 0.f;
    #pragma unroll
    for (int s = 0; s < JS; ++s) {
        f[s] = __builtin_amdgcn_exp2f(mv[s] - M);
        L += pl[((size_t)(s * 8 + bh)) * NSP + i] * f[s];
    }
    const float invL = 1.0f / L;
    #pragma unroll
    for (int d = 0; d < 32; ++d) {
        float acc = 0.f;
        #pragma unroll
        for (int s = 0; s < JS; ++s)
            acc += pacc[(((size_t)(s * 8 + bh)) * 32 + d) * NSP + i] * f[s];
        attnout[((size_t)b * CD + h * 32 + d) * NSP + i] = acc * invL;
    }
}

extern "C" void kernel_launch(void* const* d_in, const int* in_sizes, int n_in,
                              void* d_out, int out_size, void* d_ws, size_t ws_size,
                              hipStream_t stream)
{
    const float* x  = (const float*)d_in[0];
    const float* cx = (const float*)d_in[1];
    const float* Wq = (const float*)d_in[2];
    const float* bq = (const float*)d_in[3];
    const float* Wk = (const float*)d_in[4];
    const float* bk = (const float*)d_in[5];
    const float* Wv = (const float*)d_in[6];
    const float* bv = (const float*)d_in[7];
    const float* Wo = (const float*)d_in[8];
    const float* bo = (const float*)d_in[9];
    float* out = (float*)d_out;

    char* w = (char*)d_ws;
    float*  qb   = (float*)w;  w += (size_t)NB * CD * NSP * 4;        // 4 MB
    float*  kb   = (float*)w;  w += (size_t)NB * CD * NSP * 4;        // 4 MB
    float*  scq  = (float*)w;  w += 1024;
    float*  sck  = (float*)w;  w += 1024;
    ushort* Qt   = (ushort*)w; w += (size_t)NB * NH * NSP * 32 * 2;   // 2 MB
    ushort* Kt   = (ushort*)w; w += (size_t)NB * NH * NSP * 32 * 2;   // 2 MB
    ushort* V16  = (ushort*)w; w += (size_t)NB * CD * NSP * 2;        // 2 MB
    float*  pacc = (float*)w;  w += (size_t)JS * 8 * 32 * NSP * 4;    // 16 MB
    float*  pm   = (float*)w;  w += (size_t)JS * 8 * NSP * 4;         // 512 KB
    float*  pl   = (float*)w;  w += (size_t)JS * 8 * NSP * 4;         // 512 KB
    float*  attnout = (float*)w;                                      // 4 MB

    dim3 pgrid(NSP / 256, CD / 4, NB);
    proj_one<<<pgrid, 256, 0, stream>>>(x, Wq, bq, qb);
    proj_kv<<<pgrid, 256, 0, stream>>>(cx, Wk, bk, kb, Wv, bv, V16);
    rownorm<<<dim3(CD, NB, 2), 256, 0, stream>>>(qb, kb, scq, sck);
    pack_qk<<<dim3(NSP / 256, NB * NH), 256, 0, stream>>>(qb, kb, scq, sck, Qt, Kt);
    attn_mfma<<<dim3(NSP / 128, NB * NH, JS), 256, 0, stream>>>(Qt, Kt, V16, pacc, pm, pl);
    combine_kernel<<<dim3(NSP / 256, NB * NH), 256, 0, stream>>>(pacc, pm, pl, attnout);
    proj_one<<<pgrid, 256, 0, stream>>>(attnout, Wo, bo, out);
}

// Round 5
// 107.044 us; speedup vs baseline: 11.8942x; 1.0495x over previous
//
#include <hip/hip_runtime.h>
#include <math.h>

#define NSP 4096      // h*w*z = 16^3
#define CD 128        // channels
#define NB 2          // batch
#define NH 4          // heads
#define JS 4          // j-splits in attention

typedef __attribute__((ext_vector_type(8))) short bf16x8;   // 8 bf16 (4 VGPRs)
typedef __attribute__((ext_vector_type(4))) float f32x4;

static constexpr float QSCALE = 10.0f * 1.4426950408889634f;  // scale * log2(e)

__device__ __forceinline__ ushort f2bf(float f) {
    union { float f; unsigned u; } v; v.f = f;
    unsigned r = v.u + 0x7fffu + ((v.u >> 16) & 1u);   // RNE, finite inputs only
    return (ushort)(r >> 16);
}
// RNE-rounded bits: result[31:16] is the bf16 of f
__device__ __forceinline__ unsigned rnebits(float f) {
    union { float f; unsigned u; } v; v.f = f;
    return v.u + 0x7fffu + ((v.u >> 16) & 1u);
}

// ---------------- fused q,k,v projection ----------------
__global__ __launch_bounds__(256) void proj_qkv(
    const float* __restrict__ x, const float* __restrict__ cx,
    const float* __restrict__ Wq, const float* __restrict__ Bq, float* __restrict__ qb,
    const float* __restrict__ Wk, const float* __restrict__ Bk, float* __restrict__ kb,
    const float* __restrict__ Wv, const float* __restrict__ Bv, ushort* __restrict__ V16)
{
    const int n  = blockIdx.x * 256 + threadIdx.x;
    const int o0 = blockIdx.y * 4;
    const int b  = blockIdx.z;
    const float* Xb = x  + (size_t)b * CD * NSP + n;
    const float* Cb = cx + (size_t)b * CD * NSP + n;
    float aq[4], ak[4], av[4];
    #pragma unroll
    for (int r = 0; r < 4; ++r) { aq[r] = Bq[o0+r]; ak[r] = Bk[o0+r]; av[r] = Bv[o0+r]; }
    for (int c = 0; c < CD; ++c) {
        const float xv = Xb[(size_t)c * NSP];
        const float cv = Cb[(size_t)c * NSP];
        #pragma unroll
        for (int r = 0; r < 4; ++r) {
            aq[r] = fmaf(Wq[(o0 + r) * CD + c], xv, aq[r]);
            ak[r] = fmaf(Wk[(o0 + r) * CD + c], cv, ak[r]);
            av[r] = fmaf(Wv[(o0 + r) * CD + c], cv, av[r]);
        }
    }
    #pragma unroll
    for (int r = 0; r < 4; ++r) {
        qb[((size_t)b * CD + o0 + r) * NSP + n]  = aq[r];
        kb[((size_t)b * CD + o0 + r) * NSP + n]  = ak[r];
        V16[((size_t)b * CD + o0 + r) * NSP + n] = f2bf(av[r]);
    }
}

// ---------------- output projection ----------------
__global__ __launch_bounds__(256) void proj_one(
    const float* __restrict__ X, const float* __restrict__ W,
    const float* __restrict__ Bi, float* __restrict__ O)
{
    const int n  = blockIdx.x * 256 + threadIdx.x;
    const int o0 = blockIdx.y * 4;
    const int b  = blockIdx.z;
    const float* Xb = X + (size_t)b * CD * NSP + n;
    float a[4];
    #pragma unroll
    for (int r = 0; r < 4; ++r) a[r] = Bi[o0 + r];
    for (int c = 0; c < CD; ++c) {
        const float xv = Xb[(size_t)c * NSP];
        #pragma unroll
        for (int r = 0; r < 4; ++r) a[r] = fmaf(W[(o0 + r) * CD + c], xv, a[r]);
    }
    #pragma unroll
    for (int r = 0; r < 4; ++r) O[((size_t)b * CD + o0 + r) * NSP + n] = a[r];
}

// ---------------- per-(b,c)-row L2 norm scales over spatial N ----------------
__global__ __launch_bounds__(256) void rownorm(
    const float* __restrict__ qb, const float* __restrict__ kb,
    float* __restrict__ scq, float* __restrict__ sck)
{
    const int c = blockIdx.x, b = blockIdx.y, which = blockIdx.z;
    const float* row = (which ? kb : qb) + ((size_t)b * CD + c) * NSP;
    const int t = threadIdx.x;
    float ss = 0.f;
    for (int i = t * 4; i < NSP; i += 1024) {
        float4 v = *(const float4*)&row[i];
        ss = fmaf(v.x, v.x, fmaf(v.y, v.y, fmaf(v.z, v.z, fmaf(v.w, v.w, ss))));
    }
    #pragma unroll
    for (int off = 32; off > 0; off >>= 1) ss += __shfl_down(ss, off, 64);
    __shared__ float red[4];
    if ((t & 63) == 0) red[t >> 6] = ss;
    __syncthreads();
    if (t == 0) {
        const float total = red[0] + red[1] + red[2] + red[3];
        const float sc = (which ? 1.0f : QSCALE) / fmaxf(sqrtf(total), 1e-12f);
        (which ? sck : scq)[b * CD + c] = sc;
    }
}

// ---------------- pack q,k -> bf16 [bh][n][32] ----------------
__global__ __launch_bounds__(256) void pack_qk(
    const float* __restrict__ qb, const float* __restrict__ kb,
    const float* __restrict__ scq, const float* __restrict__ sck,
    ushort* __restrict__ Qt, ushort* __restrict__ Kt)
{
    const int n  = blockIdx.x * 256 + threadIdx.x;
    const int bh = blockIdx.y;
    const int b = bh >> 2, h = bh & 3;
    unsigned qw[16], kw[16];
    #pragma unroll
    for (int dp = 0; dp < 16; ++dp) {
        const int gr = b * CD + h * 32 + 2 * dp;
        const float fq0 = qb[(size_t)gr * NSP + n] * scq[gr];
        const float fq1 = qb[(size_t)(gr + 1) * NSP + n] * scq[gr + 1];
        const float fk0 = kb[(size_t)gr * NSP + n] * sck[gr];
        const float fk1 = kb[(size_t)(gr + 1) * NSP + n] * sck[gr + 1];
        qw[dp] = (unsigned)f2bf(fq0) | ((unsigned)f2bf(fq1) << 16);
        kw[dp] = (unsigned)f2bf(fk0) | ((unsigned)f2bf(fk1) << 16);
    }
    const size_t o = ((size_t)bh * NSP + n) * 32;
    #pragma unroll
    for (int j = 0; j < 4; ++j) {
        *(uint4*)(Qt + o + j * 8) = make_uint4(qw[4*j], qw[4*j+1], qw[4*j+2], qw[4*j+3]);
        *(uint4*)(Kt + o + j * 8) = make_uint4(kw[4*j], kw[4*j+1], kw[4*j+2], kw[4*j+3]);
    }
}

// ---------------- MFMA flash attention partials (no-max softmax) ----------------
// grid (NSP/128, NB*NH, JS), block 256 (4 waves). Wave: 32 queries, j-range NSP/JS.
// Swapped QK^T -> lane(g,n16): S for query n16, j-offsets {4g+r} (s0), {16+4g+r} (s1).
// P -> bf16 (software RNE + v_perm pack), redistributed to PV B-frag via 4x ds_bpermute
// with parity-keyed transmissions:
//   source (parity pp=g&1): t0=pp?X0:W0, t1=pp?X1:W1, t2=pp?W0:X0, t3=pp?W1:X1
//   dest (lowdest=g<2): aP = low?A:B, aQ = low?B:A;
//   r0=bp(aP,t0) r1=bp(aP,t1) r2=bp(aQ,t2) r3=bp(aQ,t3)
//   words = low ? {r0,r1,r2,r3} : {r2,r3,r0,r1}
__global__ __launch_bounds__(256, 4) void attn_mfma(
    const ushort* __restrict__ Qt, const ushort* __restrict__ Kt,
    const ushort* __restrict__ V16,
    float* __restrict__ pacc, float* __restrict__ pl)
{
    const int t = threadIdx.x;
    const int wid = t >> 6, lane = t & 63;
    const int g = lane >> 4, n16 = lane & 15;
    const int bh = blockIdx.y, js = blockIdx.z;
    const int b = bh >> 2, h = bh & 3;
    const int i0 = (blockIdx.x * 4 + wid) * 32;

    const ushort* Qb = Qt + (size_t)bh * NSP * 32;
    const ushort* Kb = Kt + (size_t)bh * NSP * 32;
    const ushort* Vb = V16 + (size_t)(b * CD + h * 32) * NSP;

    const bf16x8 qf0 = *(const bf16x8*)(Qb + (size_t)(i0 + n16) * 32 + g * 8);
    const bf16x8 qf1 = *(const bf16x8*)(Qb + (size_t)(i0 + 16 + n16) * 32 + g * 8);

    f32x4 acc00 = {0,0,0,0}, acc01 = {0,0,0,0}, acc10 = {0,0,0,0}, acc11 = {0,0,0,0};
    float l0 = 0.f, l1 = 0.f;
    const f32x4 zero = {0,0,0,0};

    const bool pp      = (g & 1);     // source parity
    const bool lowdest = (g < 2);     // dest wants s0-derived (W) data
    const int srcA4 = ((32 * (g & 1)) + n16) * 4;   // lane 2*(g&1)*16 + n16
    const int srcB4 = srcA4 + 64;                   // +16 lanes
    const int aP = lowdest ? srcA4 : srcB4;
    const int aQ = lowdest ? srcB4 : srcA4;

    const int jbeg = js * (NSP / JS), jend = jbeg + NSP / JS;
    for (int jt = jbeg; jt < jend; jt += 32) {
        const bf16x8 kf0 = *(const bf16x8*)(Kb + (size_t)(jt + n16) * 32 + g * 8);
        const bf16x8 kf1 = *(const bf16x8*)(Kb + (size_t)(jt + 16 + n16) * 32 + g * 8);
        const bf16x8 vf0 = *(const bf16x8*)(Vb + (size_t)n16 * NSP + jt + g * 8);
        const bf16x8 vf1 = *(const bf16x8*)(Vb + (size_t)(16 + n16) * NSP + jt + g * 8);

        #pragma unroll
        for (int it = 0; it < 2; ++it) {
            const bf16x8 qf = it ? qf1 : qf0;
            f32x4 s0 = __builtin_amdgcn_mfma_f32_16x16x32_bf16(kf0, qf, zero, 0, 0, 0);
            f32x4 s1 = __builtin_amdgcn_mfma_f32_16x16x32_bf16(kf1, qf, zero, 0, 0, 0);
            const float p0 = __builtin_amdgcn_exp2f(s0.x);
            const float p1 = __builtin_amdgcn_exp2f(s0.y);
            const float p2 = __builtin_amdgcn_exp2f(s0.z);
            const float p3 = __builtin_amdgcn_exp2f(s0.w);
            const float p4 = __builtin_amdgcn_exp2f(s1.x);
            const float p5 = __builtin_amdgcn_exp2f(s1.y);
            const float p6 = __builtin_amdgcn_exp2f(s1.z);
            const float p7 = __builtin_amdgcn_exp2f(s1.w);
            const float ps = ((p0 + p1) + (p2 + p3)) + ((p4 + p5) + (p6 + p7));
            if (it) l1 += ps; else l0 += ps;
            // RNE-round then pack high halves: low16 = bf16(first), high16 = bf16(second)
            const unsigned r0 = rnebits(p0), r1 = rnebits(p1), r2 = rnebits(p2), r3 = rnebits(p3);
            const unsigned r4 = rnebits(p4), r5 = rnebits(p5), r6 = rnebits(p6), r7 = rnebits(p7);
            const unsigned W0 = __builtin_amdgcn_perm(r1, r0, 0x07060302u);  // s0: jo 4g,4g+1
            const unsigned W1 = __builtin_amdgcn_perm(r3, r2, 0x07060302u);  // s0: jo 4g+2,4g+3
            const unsigned X0 = __builtin_amdgcn_perm(r5, r4, 0x07060302u);  // s1: jo 16+4g,+1
            const unsigned X1 = __builtin_amdgcn_perm(r7, r6, 0x07060302u);  // s1: jo 16+4g+2,+3
            const int t0 = (int)(pp ? X0 : W0);
            const int t1 = (int)(pp ? X1 : W1);
            const int t2 = (int)(pp ? W0 : X0);
            const int t3 = (int)(pp ? W1 : X1);
            const int q0 = __builtin_amdgcn_ds_bpermute(aP, t0);
            const int q1 = __builtin_amdgcn_ds_bpermute(aP, t1);
            const int q2 = __builtin_amdgcn_ds_bpermute(aQ, t2);
            const int q3 = __builtin_amdgcn_ds_bpermute(aQ, t3);
            union { int u[4]; bf16x8 v; } pu;
            pu.u[0] = lowdest ? q0 : q2;
            pu.u[1] = lowdest ? q1 : q3;
            pu.u[2] = lowdest ? q2 : q0;
            pu.u[3] = lowdest ? q3 : q1;
            if (it) {
                acc10 = __builtin_amdgcn_mfma_f32_16x16x32_bf16(vf0, pu.v, acc10, 0, 0, 0);
                acc11 = __builtin_amdgcn_mfma_f32_16x16x32_bf16(vf1, pu.v, acc11, 0, 0, 0);
            } else {
                acc00 = __builtin_amdgcn_mfma_f32_16x16x32_bf16(vf0, pu.v, acc00, 0, 0, 0);
                acc01 = __builtin_amdgcn_mfma_f32_16x16x32_bf16(vf1, pu.v, acc01, 0, 0, 0);
            }
        }
    }

    // reduce l across the 4 g-lanes of each query column
    l0 += __shfl_xor(l0, 16); l0 += __shfl_xor(l0, 32);
    l1 += __shfl_xor(l1, 16); l1 += __shfl_xor(l1, 32);

    const size_t base = (size_t)js * 8 + bh;
    if (lane < 16) {
        pl[base * NSP + i0 + n16]      = l0;
        pl[base * NSP + i0 + 16 + n16] = l1;
    }
    float* pb = pacc + base * 32 * NSP;
    #pragma unroll
    for (int r = 0; r < 4; ++r) {
        const int d0 = 4 * g + r, d1 = 16 + 4 * g + r;
        pb[(size_t)d0 * NSP + i0 + n16]      = acc00[r];
        pb[(size_t)d1 * NSP + i0 + n16]      = acc01[r];
        pb[(size_t)d0 * NSP + i0 + 16 + n16] = acc10[r];
        pb[(size_t)d1 * NSP + i0 + 16 + n16] = acc11[r];
    }
}

// ---------------- combine j-split partials (no max) ----------------
__global__ __launch_bounds__(256) void combine_kernel(
    const float* __restrict__ pacc, const float* __restrict__ pl,
    float* __restrict__ attnout)
{
    const int i  = blockIdx.x * 256 + threadIdx.x;
    const int bh = blockIdx.y;
    const int b = bh >> 2, h = bh & 3;
    float L = 0.f;
    #pragma unroll
    for (int s = 0; s < JS; ++s) L += pl[((size_t)(s * 8 + bh)) * NSP + i];
    const float invL = 1.0f / L;
    #pragma unroll
    for (int d = 0; d < 32; ++d) {
        float acc = 0.f;
        #pragma unroll
        for (int s = 0; s < JS; ++s)
            acc += pacc[(((size_t)(s * 8 + bh)) * 32 + d) * NSP + i];
        attnout[((size_t)b * CD + h * 32 + d) * NSP + i] = acc * invL;
    }
}

extern "C" void kernel_launch(void* const* d_in, const int* in_sizes, int n_in,
                              void* d_out, int out_size, void* d_ws, size_t ws_size,
                              hipStream_t stream)
{
    const float* x  = (const float*)d_in[0];
    const float* cx = (const float*)d_in[1];
    const float* Wq = (const float*)d_in[2];
    const float* bq = (const float*)d_in[3];
    const float* Wk = (const float*)d_in[4];
    const float* bk = (const float*)d_in[5];
    const float* Wv = (const float*)d_in[6];
    const float* bv = (const float*)d_in[7];
    const float* Wo = (const float*)d_in[8];
    const float* bo = (const float*)d_in[9];
    float* out = (float*)d_out;

    char* w = (char*)d_ws;
    float*  qb   = (float*)w;  w += (size_t)NB * CD * NSP * 4;        // 4 MB
    float*  kb   = (float*)w;  w += (size_t)NB * CD * NSP * 4;        // 4 MB
    float*  scq  = (float*)w;  w += 1024;
    float*  sck  = (float*)w;  w += 1024;
    ushort* Qt   = (ushort*)w; w += (size_t)NB * NH * NSP * 32 * 2;   // 2 MB
    ushort* Kt   = (ushort*)w; w += (size_t)NB * NH * NSP * 32 * 2;   // 2 MB
    ushort* V16  = (ushort*)w; w += (size_t)NB * CD * NSP * 2;        // 2 MB
    float*  pacc = (float*)w;  w += (size_t)JS * 8 * 32 * NSP * 4;    // 16 MB
    float*  pl   = (float*)w;  w += (size_t)JS * 8 * NSP * 4;         // 512 KB
    float*  attnout = (float*)w;                                      // 4 MB

    dim3 pgrid(NSP / 256, CD / 4, NB);
    proj_qkv<<<pgrid, 256, 0, stream>>>(x, cx, Wq, bq, qb, Wk, bk, kb, Wv, bv, V16);
    rownorm<<<dim3(CD, NB, 2), 256, 0, stream>>>(qb, kb, scq, sck);
    pack_qk<<<dim3(NSP / 256, NB * NH), 256, 0, stream>>>(qb, kb, scq, sck, Qt, Kt);
    attn_mfma<<<dim3(NSP / 128, NB * NH, JS), 256, 0, stream>>>(Qt, Kt, V16, pacc, pl);
    combine_kernel<<<dim3(NSP / 256, NB * NH), 256, 0, stream>>>(pacc, pl, attnout);
    proj_one<<<pgrid, 256, 0, stream>>>(attnout, Wo, bo, out);
}

// Round 6
// 98.845 us; speedup vs baseline: 12.8808x; 1.0829x over previous
//
#include <hip/hip_runtime.h>
#include <math.h>

#define NSP 4096      // h*w*z = 16^3
#define CD 128        // channels
#define NB 2          // batch
#define NH 4          // heads
#define JS 4          // j-splits in attention
#define JSTEP 64
#define NSTEP ((NSP / JS) / JSTEP)   // 16

typedef __attribute__((ext_vector_type(8))) short bf16x8;   // 8 bf16 (4 VGPRs)
typedef __attribute__((ext_vector_type(4))) float f32x4;

static constexpr float QSCALE = 10.0f * 1.4426950408889634f;  // scale * log2(e)

__device__ __forceinline__ ushort f2bf(float f) {
    union { float f; unsigned u; } v; v.f = f;
    unsigned r = v.u + 0x7fffu + ((v.u >> 16) & 1u);   // RNE, finite inputs only
    return (ushort)(r >> 16);
}
// RNE-rounded bits: result[31:16] is the bf16 of f
__device__ __forceinline__ unsigned rnebits(float f) {
    union { float f; unsigned u; } v; v.f = f;
    return v.u + 0x7fffu + ((v.u >> 16) & 1u);
}

__device__ __forceinline__ void gload_lds16(const void* g, void* l) {
    __builtin_amdgcn_global_load_lds(
        (const __attribute__((address_space(1))) unsigned int*)g,
        (__attribute__((address_space(3))) unsigned int*)l, 16, 0, 0);
}

// ---------------- fused q,k,v projection ----------------
__global__ __launch_bounds__(256) void proj_qkv(
    const float* __restrict__ x, const float* __restrict__ cx,
    const float* __restrict__ Wq, const float* __restrict__ Bq, float* __restrict__ qb,
    const float* __restrict__ Wk, const float* __restrict__ Bk, float* __restrict__ kb,
    const float* __restrict__ Wv, const float* __restrict__ Bv, ushort* __restrict__ V16)
{
    const int n  = blockIdx.x * 256 + threadIdx.x;
    const int o0 = blockIdx.y * 4;
    const int b  = blockIdx.z;
    const float* Xb = x  + (size_t)b * CD * NSP + n;
    const float* Cb = cx + (size_t)b * CD * NSP + n;
    float aq[4], ak[4], av[4];
    #pragma unroll
    for (int r = 0; r < 4; ++r) { aq[r] = Bq[o0+r]; ak[r] = Bk[o0+r]; av[r] = Bv[o0+r]; }
    for (int c = 0; c < CD; ++c) {
        const float xv = Xb[(size_t)c * NSP];
        const float cv = Cb[(size_t)c * NSP];
        #pragma unroll
        for (int r = 0; r < 4; ++r) {
            aq[r] = fmaf(Wq[(o0 + r) * CD + c], xv, aq[r]);
            ak[r] = fmaf(Wk[(o0 + r) * CD + c], cv, ak[r]);
            av[r] = fmaf(Wv[(o0 + r) * CD + c], cv, av[r]);
        }
    }
    #pragma unroll
    for (int r = 0; r < 4; ++r) {
        qb[((size_t)b * CD + o0 + r) * NSP + n]  = aq[r];
        kb[((size_t)b * CD + o0 + r) * NSP + n]  = ak[r];
        V16[((size_t)b * CD + o0 + r) * NSP + n] = f2bf(av[r]);
    }
}

// ---------------- output projection ----------------
__global__ __launch_bounds__(256) void proj_one(
    const float* __restrict__ X, const float* __restrict__ W,
    const float* __restrict__ Bi, float* __restrict__ O)
{
    const int n  = blockIdx.x * 256 + threadIdx.x;
    const int o0 = blockIdx.y * 4;
    const int b  = blockIdx.z;
    const float* Xb = X + (size_t)b * CD * NSP + n;
    float a[4];
    #pragma unroll
    for (int r = 0; r < 4; ++r) a[r] = Bi[o0 + r];
    for (int c = 0; c < CD; ++c) {
        const float xv = Xb[(size_t)c * NSP];
        #pragma unroll
        for (int r = 0; r < 4; ++r) a[r] = fmaf(W[(o0 + r) * CD + c], xv, a[r]);
    }
    #pragma unroll
    for (int r = 0; r < 4; ++r) O[((size_t)b * CD + o0 + r) * NSP + n] = a[r];
}

// ---------------- per-(b,c)-row L2 norm scales over spatial N ----------------
__global__ __launch_bounds__(256) void rownorm(
    const float* __restrict__ qb, const float* __restrict__ kb,
    float* __restrict__ scq, float* __restrict__ sck)
{
    const int c = blockIdx.x, b = blockIdx.y, which = blockIdx.z;
    const float* row = (which ? kb : qb) + ((size_t)b * CD + c) * NSP;
    const int t = threadIdx.x;
    float ss = 0.f;
    for (int i = t * 4; i < NSP; i += 1024) {
        float4 v = *(const float4*)&row[i];
        ss = fmaf(v.x, v.x, fmaf(v.y, v.y, fmaf(v.z, v.z, fmaf(v.w, v.w, ss))));
    }
    #pragma unroll
    for (int off = 32; off > 0; off >>= 1) ss += __shfl_down(ss, off, 64);
    __shared__ float red[4];
    if ((t & 63) == 0) red[t >> 6] = ss;
    __syncthreads();
    if (t == 0) {
        const float total = red[0] + red[1] + red[2] + red[3];
        const float sc = (which ? 1.0f : QSCALE) / fmaxf(sqrtf(total), 1e-12f);
        (which ? sck : scq)[b * CD + c] = sc;
    }
}

// ---------------- pack q,k -> bf16 chunk-major [bh][n/64][c=d/8][n%64][8] ----------------
// ushort index: ((bh*(NSP/64) + jb)*4 + c)*512 + jr*8 + e
__global__ __launch_bounds__(256) void pack_qk(
    const float* __restrict__ qb, const float* __restrict__ kb,
    const float* __restrict__ scq, const float* __restrict__ sck,
    ushort* __restrict__ Qt, ushort* __restrict__ Kt)
{
    const int n  = blockIdx.x * 256 + threadIdx.x;
    const int bh = blockIdx.y;
    const int b = bh >> 2, h = bh & 3;
    unsigned qw[16], kw[16];
    #pragma unroll
    for (int dp = 0; dp < 16; ++dp) {
        const int gr = b * CD + h * 32 + 2 * dp;
        const float fq0 = qb[(size_t)gr * NSP + n] * scq[gr];
        const float fq1 = qb[(size_t)(gr + 1) * NSP + n] * scq[gr + 1];
        const float fk0 = kb[(size_t)gr * NSP + n] * sck[gr];
        const float fk1 = kb[(size_t)(gr + 1) * NSP + n] * sck[gr + 1];
        qw[dp] = (unsigned)f2bf(fq0) | ((unsigned)f2bf(fq1) << 16);
        kw[dp] = (unsigned)f2bf(fk0) | ((unsigned)f2bf(fk1) << 16);
    }
    const int jb = n >> 6, jr = n & 63;
    const size_t base = ((size_t)(bh * (NSP / 64) + jb)) * 4;
    #pragma unroll
    for (int c = 0; c < 4; ++c) {
        *(uint4*)(Qt + (base + c) * 512 + jr * 8) =
            make_uint4(qw[4*c], qw[4*c+1], qw[4*c+2], qw[4*c+3]);
        *(uint4*)(Kt + (base + c) * 512 + jr * 8) =
            make_uint4(kw[4*c], kw[4*c+1], kw[4*c+2], kw[4*c+3]);
    }
}

// ---------------- MFMA flash attention partials (LDS-staged K/V) ----------------
// 1-D grid 1024 blocks, 256 threads (4 waves). XCD-friendly decode:
// bh = f&7, i-tile = (f>>3)&31, js = f>>8  -> 32 blocks sharing (bh,js) are
// 8 apart in flat id (same XCD under round-robin dispatch).
// Per block: stage K (chunk-major, linear) and V (XOR-swizzled source) tiles of
// JSTEP=64 j into LDS, double-buffered; 4 waves share; each wave owns 32 queries.
__global__ __launch_bounds__(256, 4) void attn_mfma(
    const ushort* __restrict__ Qt, const ushort* __restrict__ Kt,
    const ushort* __restrict__ V16,
    float* __restrict__ pacc, float* __restrict__ pl)
{
    __shared__ __align__(16) ushort Kl[2][2048];   // [c=d/8][64 j][8]  (4KB each)
    __shared__ __align__(16) ushort Vl[2][2048];   // [d][8 chunks^swz][8] (4KB each)

    const int t = threadIdx.x;
    const int wid = t >> 6, lane = t & 63;
    const int g = lane >> 4, n16 = lane & 15;
    const int f = blockIdx.x;
    const int bh = f & 7, it32 = (f >> 3) & 31, js = f >> 8;
    const int b = bh >> 2, h = bh & 3;
    const int i0 = it32 * 128 + wid * 32;

    const ushort* QtB = Qt + (size_t)bh * NSP * 32;   // chunked, contiguous per bh
    const ushort* KtB = Kt + (size_t)bh * NSP * 32;
    const ushort* Vb  = V16 + (size_t)(b * CD + h * 32) * NSP;

    // Q fragments (once): chunk-major global read
    const size_t qoff = ((size_t)(i0 >> 6) * 4 + g) * 512 + (size_t)(i0 & 32) * 8;
    const bf16x8 qf0 = *(const bf16x8*)(QtB + qoff + n16 * 8);
    const bf16x8 qf1 = *(const bf16x8*)(QtB + qoff + (16 + n16) * 8);

    f32x4 acc00 = {0,0,0,0}, acc01 = {0,0,0,0}, acc10 = {0,0,0,0}, acc11 = {0,0,0,0};
    float l0 = 0.f, l1 = 0.f;
    const f32x4 zero = {0,0,0,0};

    const bool pp      = (g & 1);
    const bool lowdest = (g < 2);
    const int srcA4 = ((32 * (g & 1)) + n16) * 4;
    const int srcB4 = srcA4 + 64;
    const int aP = lowdest ? srcA4 : srcB4;
    const int aQ = lowdest ? srcB4 : srcA4;

    // staging helpers (wave-uniform LDS base; HW appends lane*16)
    const int vd  = wid * 8 + (lane >> 3);          // V row this lane fetches
    const int vsw = (lane & 7) ^ (lane >> 3);       // swizzled source chunk
    auto stageK = [&](int buf, int jt) {
        const ushort* gsrc = KtB + ((size_t)(jt >> 6) * 4 + wid) * 512 + lane * 8;
        gload_lds16(gsrc, &Kl[buf][wid * 512]);
    };
    auto stageV = [&](int buf, int jt) {
        const ushort* gsrc = Vb + (size_t)vd * NSP + jt + vsw * 8;
        gload_lds16(gsrc, &Vl[buf][wid * 512]);
    };

    const int jbeg = js * (NSP / JS);

    stageK(0, jbeg); stageV(0, jbeg);
    __syncthreads();

    int cur = 0;
    for (int step = 0; step < NSTEP; ++step) {
        const int jt = jbeg + step * JSTEP;
        if (step + 1 < NSTEP) { stageK(cur ^ 1, jt + JSTEP); stageV(cur ^ 1, jt + JSTEP); }

        #pragma unroll
        for (int s = 0; s < 2; ++s) {
            const bf16x8 kf0 = *(const bf16x8*)(&Kl[cur][g * 512 + (s * 32 + n16) * 8]);
            const bf16x8 kf1 = *(const bf16x8*)(&Kl[cur][g * 512 + (s * 32 + 16 + n16) * 8]);
            const int vc = ((s * 4 + g) ^ (n16 & 7)) * 8;
            const bf16x8 vf0 = *(const bf16x8*)(&Vl[cur][n16 * 64 + vc]);
            const bf16x8 vf1 = *(const bf16x8*)(&Vl[cur][(16 + n16) * 64 + vc]);

            #pragma unroll
            for (int it = 0; it < 2; ++it) {
                const bf16x8 qf = it ? qf1 : qf0;
                f32x4 s0 = __builtin_amdgcn_mfma_f32_16x16x32_bf16(kf0, qf, zero, 0, 0, 0);
                f32x4 s1 = __builtin_amdgcn_mfma_f32_16x16x32_bf16(kf1, qf, zero, 0, 0, 0);
                const float p0 = __builtin_amdgcn_exp2f(s0.x);
                const float p1 = __builtin_amdgcn_exp2f(s0.y);
                const float p2 = __builtin_amdgcn_exp2f(s0.z);
                const float p3 = __builtin_amdgcn_exp2f(s0.w);
                const float p4 = __builtin_amdgcn_exp2f(s1.x);
                const float p5 = __builtin_amdgcn_exp2f(s1.y);
                const float p6 = __builtin_amdgcn_exp2f(s1.z);
                const float p7 = __builtin_amdgcn_exp2f(s1.w);
                const float ps = ((p0 + p1) + (p2 + p3)) + ((p4 + p5) + (p6 + p7));
                if (it) l1 += ps; else l0 += ps;
                const unsigned r0 = rnebits(p0), r1 = rnebits(p1), r2 = rnebits(p2), r3 = rnebits(p3);
                const unsigned r4 = rnebits(p4), r5 = rnebits(p5), r6 = rnebits(p6), r7 = rnebits(p7);
                const unsigned W0 = __builtin_amdgcn_perm(r1, r0, 0x07060302u);
                const unsigned W1 = __builtin_amdgcn_perm(r3, r2, 0x07060302u);
                const unsigned X0 = __builtin_amdgcn_perm(r5, r4, 0x07060302u);
                const unsigned X1 = __builtin_amdgcn_perm(r7, r6, 0x07060302u);
                const int t0 = (int)(pp ? X0 : W0);
                const int t1 = (int)(pp ? X1 : W1);
                const int t2 = (int)(pp ? W0 : X0);
                const int t3 = (int)(pp ? W1 : X1);
                const int q0 = __builtin_amdgcn_ds_bpermute(aP, t0);
                const int q1 = __builtin_amdgcn_ds_bpermute(aP, t1);
                const int q2 = __builtin_amdgcn_ds_bpermute(aQ, t2);
                const int q3 = __builtin_amdgcn_ds_bpermute(aQ, t3);
                union { int u[4]; bf16x8 v; } pu;
                pu.u[0] = lowdest ? q0 : q2;
                pu.u[1] = lowdest ? q1 : q3;
                pu.u[2] = lowdest ? q2 : q0;
                pu.u[3] = lowdest ? q3 : q1;
                if (it) {
                    acc10 = __builtin_amdgcn_mfma_f32_16x16x32_bf16(vf0, pu.v, acc10, 0, 0, 0);
                    acc11 = __builtin_amdgcn_mfma_f32_16x16x32_bf16(vf1, pu.v, acc11, 0, 0, 0);
                } else {
                    acc00 = __builtin_amdgcn_mfma_f32_16x16x32_bf16(vf0, pu.v, acc00, 0, 0, 0);
                    acc01 = __builtin_amdgcn_mfma_f32_16x16x32_bf16(vf1, pu.v, acc01, 0, 0, 0);
                }
            }
        }
        __syncthreads();   // drains vmcnt (stage of cur^1 done) + all waves past cur
        cur ^= 1;
    }

    // reduce l across the 4 g-lanes of each query column
    l0 += __shfl_xor(l0, 16); l0 += __shfl_xor(l0, 32);
    l1 += __shfl_xor(l1, 16); l1 += __shfl_xor(l1, 32);

    const size_t base = (size_t)js * 8 + bh;
    if (lane < 16) {
        pl[base * NSP + i0 + n16]      = l0;
        pl[base * NSP + i0 + 16 + n16] = l1;
    }
    float* pb = pacc + base * 32 * NSP;
    #pragma unroll
    for (int r = 0; r < 4; ++r) {
        const int d0 = 4 * g + r, d1 = 16 + 4 * g + r;
        pb[(size_t)d0 * NSP + i0 + n16]      = acc00[r];
        pb[(size_t)d1 * NSP + i0 + n16]      = acc01[r];
        pb[(size_t)d0 * NSP + i0 + 16 + n16] = acc10[r];
        pb[(size_t)d1 * NSP + i0 + 16 + n16] = acc11[r];
    }
}

// ---------------- combine j-split partials (no max) ----------------
__global__ __launch_bounds__(256) void combine_kernel(
    const float* __restrict__ pacc, const float* __restrict__ pl,
    float* __restrict__ attnout)
{
    const int i  = blockIdx.x * 256 + threadIdx.x;
    const int bh = blockIdx.y;
    const int b = bh >> 2, h = bh & 3;
    float L = 0.f;
    #pragma unroll
    for (int s = 0; s < JS; ++s) L += pl[((size_t)(s * 8 + bh)) * NSP + i];
    const float invL = 1.0f / L;
    #pragma unroll
    for (int d = 0; d < 32; ++d) {
        float acc = 0.f;
        #pragma unroll
        for (int s = 0; s < JS; ++s)
            acc += pacc[(((size_t)(s * 8 + bh)) * 32 + d) * NSP + i];
        attnout[((size_t)b * CD + h * 32 + d) * NSP + i] = acc * invL;
    }
}

extern "C" void kernel_launch(void* const* d_in, const int* in_sizes, int n_in,
                              void* d_out, int out_size, void* d_ws, size_t ws_size,
                              hipStream_t stream)
{
    const float* x  = (const float*)d_in[0];
    const float* cx = (const float*)d_in[1];
    const float* Wq = (const float*)d_in[2];
    const float* bq = (const float*)d_in[3];
    const float* Wk = (const float*)d_in[4];
    const float* bk = (const float*)d_in[5];
    const float* Wv = (const float*)d_in[6];
    const float* bv = (const float*)d_in[7];
    const float* Wo = (const float*)d_in[8];
    const float* bo = (const float*)d_in[9];
    float* out = (float*)d_out;

    char* w = (char*)d_ws;
    float*  qb   = (float*)w;  w += (size_t)NB * CD * NSP * 4;        // 4 MB
    float*  kb   = (float*)w;  w += (size_t)NB * CD * NSP * 4;        // 4 MB
    float*  scq  = (float*)w;  w += 1024;
    float*  sck  = (float*)w;  w += 1024;
    ushort* Qt   = (ushort*)w; w += (size_t)NB * NH * NSP * 32 * 2;   // 2 MB
    ushort* Kt   = (ushort*)w; w += (size_t)NB * NH * NSP * 32 * 2;   // 2 MB
    ushort* V16  = (ushort*)w; w += (size_t)NB * CD * NSP * 2;        // 2 MB
    float*  pacc = (float*)w;  w += (size_t)JS * 8 * 32 * NSP * 4;    // 16 MB
    float*  pl   = (float*)w;  w += (size_t)JS * 8 * NSP * 4;         // 512 KB
    float*  attnout = (float*)w;                                      // 4 MB

    dim3 pgrid(NSP / 256, CD / 4, NB);
    proj_qkv<<<pgrid, 256, 0, stream>>>(x, cx, Wq, bq, qb, Wk, bk, kb, Wv, bv, V16);
    rownorm<<<dim3(CD, NB, 2), 256, 0, stream>>>(qb, kb, scq, sck);
    pack_qk<<<dim3(NSP / 256, NB * NH), 256, 0, stream>>>(qb, kb, scq, sck, Qt, Kt);
    attn_mfma<<<dim3(1024), 256, 0, stream>>>(Qt, Kt, V16, pacc, pl);
    combine_kernel<<<dim3(NSP / 256, NB * NH), 256, 0, stream>>>(pacc, pl, attnout);
    proj_one<<<pgrid, 256, 0, stream>>>(attnout, Wo, bo, out);
}